// Round 1
// baseline (84.000 us; speedup 1.0000x reference)
//
#include <hip/hip_runtime.h>

// out[b, f*64+n] = sum_c sum_m w[f,c,m] * x[b, c*64 + (n-m) mod 64]
//   == X (256x4096) @ Bt^T, Bt[f*64+n][c*64+j] = w[f,c,(n-j)&63]
// 3 kernels: x->bf16, weight->circulant-expanded bf16 Bt, bf16 MFMA GEMM.

#define KDIM 4096
#define NDIM 4096
#define MDIM 256

#define BM 64
#define BN 128
#define BK 64

typedef __attribute__((ext_vector_type(8))) short s16x8;
typedef __attribute__((ext_vector_type(4))) float f32x4;

__device__ __forceinline__ unsigned short f2bf(float f) {
  unsigned int u = __float_as_uint(f);
  u += 0x7FFF + ((u >> 16) & 1);   // round-to-nearest-even
  return (unsigned short)(u >> 16);
}

// ---- x (fp32, 256x4096) -> bf16 ----
__global__ __launch_bounds__(256) void xconv_kernel(const float* __restrict__ x,
                                                    unsigned short* __restrict__ Xb) {
  int i = blockIdx.x * 256 + threadIdx.x;   // 4 elements per thread
  float4 v = ((const float4*)x)[i];
  union { unsigned short u[4]; uint2 v2; } o;
  o.u[0] = f2bf(v.x); o.u[1] = f2bf(v.y); o.u[2] = f2bf(v.z); o.u[3] = f2bf(v.w);
  *(uint2*)(Xb + (size_t)i * 4) = o.v2;
}

// ---- weights (F=64,C=64,K=64 fp32) -> Bt bf16 [4096][4096] ----
// Bt[f*64+n][c*64+j] = w[f][c][(n-j)&63]
__global__ __launch_bounds__(256) void expand_kernel(const float* __restrict__ w,
                                                     unsigned short* __restrict__ Bt) {
  __shared__ unsigned short wl[4][64];
  const int tid = threadIdx.x;
  const int sub = tid >> 6;
  const int lane = tid & 63;
  const int p = blockIdx.x * 4 + sub;         // p = f*64 + c
  wl[sub][lane] = f2bf(w[(size_t)p * 64 + lane]);
  __syncthreads();
  const int f = p >> 6, c = p & 63;
  const int n = lane;
  size_t rowbase = (size_t)(f * 64 + n) * KDIM + c * 64;
  for (int j0 = 0; j0 < 64; j0 += 8) {
    union { unsigned short u[8]; uint4 v; } buf;
    #pragma unroll
    for (int t = 0; t < 8; ++t) buf.u[t] = wl[sub][(n - j0 - t) & 63];
    *(uint4*)(Bt + rowbase + j0) = buf.v;
  }
}

// ---- GEMM: out(256x4096 fp32) = Xb(256x4096 bf16) @ Bt(4096x4096 bf16, row=out-col) ----
__global__ __launch_bounds__(256) void gemm_kernel(const unsigned short* __restrict__ A,
                                                   const unsigned short* __restrict__ Bt,
                                                   float* __restrict__ out) {
  __shared__ unsigned short As[BM * BK];   // [64][64]  8 KB
  __shared__ unsigned short Bs[BN * BK];   // [128][64] 16 KB
  const int tid = threadIdx.x;
  const int lane = tid & 63;
  const int wid = tid >> 6;
  const int wm = wid >> 1;         // 2 waves along M
  const int wn = wid & 1;          // 2 waves along N
  const int row0 = blockIdx.y * BM;
  const int col0 = blockIdx.x * BN;

  f32x4 acc[2][4] = {};

  for (int k0 = 0; k0 < KDIM; k0 += BK) {
    __syncthreads();
    // stage A tile: 64x64 bf16 = 8KB = 2 chunks of (256 thr x 16B)
    #pragma unroll
    for (int ch = 0; ch < 2; ++ch) {
      int e = (ch * 4096 + tid * 16) >> 1;     // element index in As
      int r = e >> 6, c = e & 63;
      __builtin_amdgcn_global_load_lds(
          (const __attribute__((address_space(1))) void*)(A + (size_t)(row0 + r) * KDIM + k0 + c),
          (__attribute__((address_space(3))) void*)(As + e), 16, 0, 0);
    }
    // stage B tile: 128x64 bf16 = 16KB = 4 chunks
    #pragma unroll
    for (int ch = 0; ch < 4; ++ch) {
      int e = (ch * 4096 + tid * 16) >> 1;
      int r = e >> 6, c = e & 63;
      __builtin_amdgcn_global_load_lds(
          (const __attribute__((address_space(1))) void*)(Bt + (size_t)(col0 + r) * KDIM + k0 + c),
          (__attribute__((address_space(3))) void*)(Bs + e), 16, 0, 0);
    }
    __syncthreads();  // compiler emits s_waitcnt vmcnt(0) before s_barrier

    #pragma unroll
    for (int kk = 0; kk < 2; ++kk) {
      s16x8 a[2], b[4];
      #pragma unroll
      for (int m = 0; m < 2; ++m)
        a[m] = *(const s16x8*)(As + (wm * 32 + m * 16 + (lane & 15)) * 64 + kk * 32 + (lane >> 4) * 8);
      #pragma unroll
      for (int n = 0; n < 4; ++n)
        b[n] = *(const s16x8*)(Bs + (wn * 64 + n * 16 + (lane & 15)) * 64 + kk * 32 + (lane >> 4) * 8);
      #pragma unroll
      for (int m = 0; m < 2; ++m)
        #pragma unroll
        for (int n = 0; n < 4; ++n)
          acc[m][n] = __builtin_amdgcn_mfma_f32_16x16x32_bf16(a[m], b[n], acc[m][n], 0, 0, 0);
    }
  }

  // epilogue: D[row][col], row = (lane>>4)*4 + r, col = lane&15 (m89-verified layout)
  #pragma unroll
  for (int m = 0; m < 2; ++m)
    #pragma unroll
    for (int n = 0; n < 4; ++n)
      #pragma unroll
      for (int r = 0; r < 4; ++r) {
        int row = row0 + wm * 32 + m * 16 + (lane >> 4) * 4 + r;
        int col = col0 + wn * 64 + n * 16 + (lane & 15);
        out[(size_t)row * NDIM + col] = acc[m][n][r];
      }
}

extern "C" void kernel_launch(void* const* d_in, const int* in_sizes, int n_in,
                              void* d_out, int out_size, void* d_ws, size_t ws_size,
                              hipStream_t stream) {
  const float* x = (const float*)d_in[0];      // (256, 4096) fp32
  const float* w = (const float*)d_in[1];      // (64, 64, 64) fp32
  float* out = (float*)d_out;                  // (256, 4096) fp32

  unsigned short* Bt = (unsigned short*)d_ws;                        // 32 MB
  unsigned short* Xb = (unsigned short*)d_ws + (size_t)NDIM * KDIM;  // +2 MB

  xconv_kernel<<<MDIM * KDIM / 4 / 256, 256, 0, stream>>>(x, Xb);
  expand_kernel<<<64 * 64 / 4, 256, 0, stream>>>(w, Bt);
  gemm_kernel<<<dim3(NDIM / BN, MDIM / BM), 256, 0, stream>>>(Xb, Bt, out);
}

// Round 2
// 35.813 us; speedup vs baseline: 2.3455x; 2.3455x over previous
//
#include <hip/hip_runtime.h>

// out[b, f*64+n] = sum_c sum_j Xb[b, c*64+j] * w[f, c, (n-j)&63]
// Fused-circulant GEMM: B-tile (one f, one c per K-step) is generated in LDS
// from the 64-float w row as 8 rotation copies -> aligned ds_read_b128 frags.
// Split-K=2 into fp32 partials (deterministic), then reduce. No Bt in HBM.

#define KDIM 4096
#define NDIM 4096
#define MDIM 256
#define BM 64
#define BN 64
#define BK 64
#define KSPLIT 2

typedef __attribute__((ext_vector_type(8))) short s16x8;
typedef __attribute__((ext_vector_type(4))) float f32x4;

__device__ __forceinline__ unsigned short f2bf(float f) {
  unsigned int u = __float_as_uint(f);
  u += 0x7FFF + ((u >> 16) & 1);   // round-to-nearest-even
  return (unsigned short)(u >> 16);
}

// ---- x (fp32, 256x4096) -> bf16 ----
__global__ __launch_bounds__(256) void xconv_kernel(const float* __restrict__ x,
                                                    unsigned short* __restrict__ Xb) {
  int i = blockIdx.x * 256 + threadIdx.x;   // 4 elements per thread
  float4 v = ((const float4*)x)[i];
  union { unsigned short u[4]; uint2 v2; } o;
  o.u[0] = f2bf(v.x); o.u[1] = f2bf(v.y); o.u[2] = f2bf(v.z); o.u[3] = f2bf(v.w);
  *(uint2*)(Xb + (size_t)i * 4) = o.v2;
}

// ---- fused GEMM: P[z] += Xb(256x4096) @ circulant(w)^T over K range z ----
__global__ __launch_bounds__(256) void gemm_fused(const unsigned short* __restrict__ Xb,
                                                  const float* __restrict__ w,
                                                  float* __restrict__ P) {
  // LDS: swizzled A tile, 8 rotated w-row copies (stride 72 u16 = 144B => +4 banks
  // per copy, worst-case 2-way conflict = free), raw fp32 w[f] row.
  __shared__ __align__(16) unsigned short As[BM * BK];   // 8 KB
  __shared__ __align__(16) unsigned short Cs[8 * 72];    // 1152 B
  __shared__ __align__(16) float wL[64 * 64];            // 16 KB  w[f][c][t]

  const int tid = threadIdx.x;
  const int lane = tid & 63;
  const int wid = tid >> 6;
  const int wm = wid >> 1;            // 2 waves along M
  const int wn = wid & 1;             // 2 waves along N
  const int lane15 = lane & 15;
  const int lhi = lane >> 4;          // 0..3
  const int f = blockIdx.x;           // 64 -> one f per block; id%8=f%8 groups per XCD
  const int row0 = blockIdx.y * BM;   // 4
  const int ks = blockIdx.z;          // KSPLIT

  // stage w[f] row: 4096 fp32 = 16 KB, linear
  #pragma unroll
  for (int ch = 0; ch < 4; ++ch) {
    int off = ch * 1024 + tid * 4;
    __builtin_amdgcn_global_load_lds(
        (const __attribute__((address_space(1))) void*)(w + (size_t)f * 4096 + off),
        (__attribute__((address_space(3))) void*)(wL + off), 16, 0, 0);
  }

  // A staging: linear LDS dest d, source pre-inverse-swizzled (G21): content at d
  // = tile[row(d)][ ((d ^ ((row&7)<<4)) & 127) >> 1 ]
  const unsigned short* srcA[2];
  int dstA[2];
  #pragma unroll
  for (int ch = 0; ch < 2; ++ch) {
    int d = ch * 4096 + tid * 16;
    int rw = d >> 7;
    int cb = (d ^ ((rw & 7) << 4)) & 127;
    srcA[ch] = Xb + (size_t)(row0 + rw) * KDIM + (cb >> 1);
    dstA[ch] = d;
  }

  const int xorv = (lane & 7) << 4;        // As read swizzle (row&7 == lane&7)
  const int mcopy = (-(lane & 7)) & 7;     // which rotation copy this lane reads
  const int bbase = mcopy * 71;            // mcopy*72 + (i0 - mcopy) = mcopy*71 + i0

  f32x4 acc[2][2] = {};

  const int kbeg = ks * (KDIM / KSPLIT);
  for (int k0 = kbeg; k0 < kbeg + KDIM / KSPLIT; k0 += BK) {
    __syncthreads();   // prev-iter fragment reads done; wL ready on first iter
    // stage A tile (64x64 bf16, 8 KB = 2 chunks of 256thr x 16B)
    #pragma unroll
    for (int ch = 0; ch < 2; ++ch) {
      __builtin_amdgcn_global_load_lds(
          (const __attribute__((address_space(1))) void*)(srcA[ch] + k0),
          (__attribute__((address_space(3))) void*)((char*)As + dstA[ch]), 16, 0, 0);
    }
    // build 8 rotated copies of w[f][c][:]: Cs[m*72+i] = bf16(w[f][c][(-i-m)&63])
    {
      const int c = k0 >> 6;
      #pragma unroll
      for (int q = 0; q < 2; ++q) {
        int v = q * 256 + tid;
        int m = v >> 6, i = v & 63;
        int idx = (0 - i - m) & 63;
        Cs[m * 72 + i] = f2bf(wL[c * 64 + idx]);
      }
    }
    __syncthreads();   // vmcnt(0)+lgkmcnt(0) drained by compiler before barrier

    #pragma unroll
    for (int kk = 0; kk < 2; ++kk) {
      const int j0 = kk * 32 + lhi * 8;
      s16x8 a[2], b[2];
      #pragma unroll
      for (int mm = 0; mm < 2; ++mm) {
        int R = wm * 32 + mm * 16 + lane15;
        a[mm] = *(const s16x8*)((const char*)As + ((R * 128 + kk * 64 + lhi * 16) ^ xorv));
      }
      #pragma unroll
      for (int nn = 0; nn < 2; ++nn) {
        int i0 = (j0 - (wn * 32 + nn * 16 + lane15)) & 63;
        b[nn] = *(const s16x8*)(Cs + bbase + i0);   // aligned b128, conflict-free
      }
      #pragma unroll
      for (int mm = 0; mm < 2; ++mm)
        #pragma unroll
        for (int nn = 0; nn < 2; ++nn)
          acc[mm][nn] = __builtin_amdgcn_mfma_f32_16x16x32_bf16(a[mm], b[nn], acc[mm][nn], 0, 0, 0);
    }
  }

  // epilogue -> partials P[ks]  (D layout: row=(lane>>4)*4+r, col=lane&15; m89)
  float* Pz = P + ((size_t)ks << 20);
  const int col0 = f * 64;
  #pragma unroll
  for (int mm = 0; mm < 2; ++mm)
    #pragma unroll
    for (int nn = 0; nn < 2; ++nn)
      #pragma unroll
      for (int r = 0; r < 4; ++r) {
        int row = row0 + wm * 32 + mm * 16 + lhi * 4 + r;
        int col = col0 + wn * 32 + nn * 16 + lane15;
        Pz[(size_t)row * NDIM + col] = acc[mm][nn][r];
      }
}

// ---- out = P[0] + P[1] ----
__global__ __launch_bounds__(256) void reduce_kernel(const float* __restrict__ P,
                                                     float* __restrict__ out) {
  size_t i = (size_t)blockIdx.x * 256 + threadIdx.x;
  f32x4 a = ((const f32x4*)P)[i];
  f32x4 b = ((const f32x4*)(P + (1u << 20)))[i];
  ((f32x4*)out)[i] = a + b;
}

extern "C" void kernel_launch(void* const* d_in, const int* in_sizes, int n_in,
                              void* d_out, int out_size, void* d_ws, size_t ws_size,
                              hipStream_t stream) {
  const float* x = (const float*)d_in[0];      // (256, 4096) fp32
  const float* w = (const float*)d_in[1];      // (64, 64, 64) fp32
  float* out = (float*)d_out;                  // (256, 4096) fp32

  unsigned short* Xb = (unsigned short*)d_ws;                    // 2 MB bf16 X
  float* P = (float*)((char*)d_ws + (2u << 20));                 // 2 x 4 MB partials

  xconv_kernel<<<MDIM * KDIM / 4 / 256, 256, 0, stream>>>(x, Xb);
  gemm_fused<<<dim3(64, 4, KSPLIT), 256, 0, stream>>>(Xb, w, P);
  reduce_kernel<<<MDIM * NDIM / 4 / 256, 256, 0, stream>>>(P, out);
}

// Round 3
// 27.957 us; speedup vs baseline: 3.0047x; 1.2810x over previous
//
#include <hip/hip_runtime.h>

// out[b, f*64+n] = sum_c sum_j Xb[b, c*64+j] * w[f, c, (n-j)&63]
// One block per (f, 64-row batch quarter) = 256 blocks = 1/CU.
// 4 waves split K (each wave owns c = 4t+wid in macro t); wave tile 64x64
// (4x4 frags of mfma 16x16x32 bf16); A-tile 64x256 double-buffered in LDS
// with XOR swizzle; circulant B built per-wave in LDS from 1 coalesced
// w-load/lane (8 rotation copies, stride 72 -> aligned conflict-lite b128).
// Cross-wave K-reduce via LDS at the end. No partials in HBM.

#define KDIM 4096
#define NMACRO 16   // 16 macros x 256 K

typedef __attribute__((ext_vector_type(8))) short s16x8;
typedef __attribute__((ext_vector_type(4))) float f32x4;
typedef unsigned short u16;

__device__ __forceinline__ u16 f2bf(float f) {
  unsigned int u = __float_as_uint(f);
  u += 0x7FFF + ((u >> 16) & 1);   // round-to-nearest-even
  return (u16)(u >> 16);
}

// ---- x (fp32, 256x4096) -> bf16 ----
__global__ __launch_bounds__(256) void xconv_kernel(const float* __restrict__ x,
                                                    u16* __restrict__ Xb) {
  int i = blockIdx.x * 256 + threadIdx.x;   // 4 elements per thread
  float4 v = ((const float4*)x)[i];
  union { u16 u[4]; uint2 v2; } o;
  o.u[0] = f2bf(v.x); o.u[1] = f2bf(v.y); o.u[2] = f2bf(v.z); o.u[3] = f2bf(v.w);
  *(uint2*)(Xb + (size_t)i * 4) = o.v2;
}

// ---- fused circulant GEMM ----
__global__ __launch_bounds__(256) void gemm_circ(const u16* __restrict__ Xb,
                                                 const float* __restrict__ w,
                                                 float* __restrict__ out) {
  extern __shared__ char pool[];            // 70144 B
  u16* Ab = (u16*)pool;                     // 2 x 16384 u16 (2 x 32 KB), swizzled
  u16* Cs = (u16*)(pool + 65536);           // 4 waves x 576 u16 (8 copies x 72)

  const int tid  = threadIdx.x;
  const int lane = tid & 63;
  const int wid  = tid >> 6;
  const int l15  = lane & 15;
  const int lq   = lane >> 4;               // 0..3
  const int f    = blockIdx.x;              // 64
  const int row0 = blockIdx.y * 64;         // 4 quarters of batch

  u16* CsW = Cs + wid * 576;                // wave-private circulant table

  // per-thread A staging addressing (8 chunks of 16B per macro), G21 both-sides
  // swizzle: linear LDS dest d; source column = (d&511) ^ ((row&15)<<4)
  const u16* asrc[8];
  int adst[8];
  #pragma unroll
  for (int ch = 0; ch < 8; ++ch) {
    int d   = ch * 4096 + tid * 16;         // byte offset in one 32KB buffer
    int row = d >> 9;                       // 512B per row (256 x bf16)
    int sb  = (d & 511) ^ ((row & 15) << 4);
    asrc[ch] = Xb + (size_t)(row0 + row) * KDIM + (sb >> 1);
    adst[ch] = d;
  }

  // w source: lane loads w[f][c][lane], c = 4t + wid -> advance 256 floats/macro
  const float* wsrc = w + (size_t)f * 4096 + wid * 64 + lane;

  // ---- prologue: stage macro 0 into Ab[0]; build Cs for macro 0
  #pragma unroll
  for (int ch = 0; ch < 8; ++ch)
    __builtin_amdgcn_global_load_lds(
        (const __attribute__((address_space(1))) void*)(asrc[ch]),
        (__attribute__((address_space(3))) void*)((char*)Ab + adst[ch]), 16, 0, 0);
  {
    float vw0 = wsrc[0];
    u16 bv = f2bf(vw0);                      // compiler inserts vmcnt wait
    #pragma unroll
    for (int m = 0; m < 8; ++m) {
      int i = (-(lane + m)) & 63;            // content C_m[i] = w[(-i-m)&63]
      CsW[m * 72 + i] = bv;
      if (i < 8) CsW[m * 72 + i + 64] = bv;  // periodic duplicate
    }
  }
  __syncthreads();                           // stage(0) drained

  f32x4 acc[4][4] = {};

  for (int t = 0; t < NMACRO; ++t) {
    const int par = t & 1;
    float vw;
    if (t + 1 < NMACRO) {
      // issue stage of macro t+1 into the other buffer (drains at barrier)
      #pragma unroll
      for (int ch = 0; ch < 8; ++ch)
        __builtin_amdgcn_global_load_lds(
            (const __attribute__((address_space(1))) void*)(asrc[ch] + (t + 1) * 256),
            (__attribute__((address_space(3))) void*)((char*)Ab + (par ^ 1) * 32768 + adst[ch]),
            16, 0, 0);
      vw = wsrc[(t + 1) * 256];              // w row for next macro's c
    }

    // ---- compute macro t: this wave's c-slice is k' in [wid*64, wid*64+64)
    const char* Abase = (const char*)Ab + par * 32768;
    #pragma unroll
    for (int kk = 0; kk < 2; ++kk) {
      s16x8 a[4], b[4];
      #pragma unroll
      for (int mm = 0; mm < 4; ++mm) {
        int row = mm * 16 + l15;
        int kq  = wid * 64 + kk * 32 + lq * 8;
        a[mm] = *(const s16x8*)(Abase + row * 512 + ((kq * 2) ^ ((row & 15) << 4)));
      }
      #pragma unroll
      for (int nn = 0; nn < 4; ++nn) {
        int i0 = ((kk * 32 + lq * 8) - (nn * 16 + l15)) & 63;
        int ae = (i0 & 7) * 71 + i0;         // = (i0&7)*72 + (i0 - (i0&7)), 8-aligned
        b[nn] = *(const s16x8*)(CsW + ae);
      }
      #pragma unroll
      for (int mm = 0; mm < 4; ++mm)
        #pragma unroll
        for (int nn = 0; nn < 4; ++nn)
          acc[mm][nn] = __builtin_amdgcn_mfma_f32_16x16x32_bf16(a[mm], b[nn], acc[mm][nn], 0, 0, 0);
    }

    // ---- build next macro's circulant table (wave-private; in-order DS is safe)
    if (t + 1 < NMACRO) {
      u16 nb = f2bf(vw);                     // vmcnt wait lands here
      #pragma unroll
      for (int m = 0; m < 8; ++m) {
        int i = (-(lane + m)) & 63;
        CsW[m * 72 + i] = nb;
        if (i < 8) CsW[m * 72 + i + 64] = nb;
      }
    }
    __syncthreads();                         // A dbuf handoff
  }

  // ---- epilogue: 4-way cross-wave K-reduce via LDS (reuse A region), store
  float* red = (float*)pool;                 // 4 x 4096 f32 = 64 KB
  float* rw  = red + wid * 4096;
  #pragma unroll
  for (int mm = 0; mm < 4; ++mm)
    #pragma unroll
    for (int nn = 0; nn < 4; ++nn)
      #pragma unroll
      for (int r = 0; r < 4; ++r) {
        int row = mm * 16 + lq * 4 + r;      // m89-verified C/D layout
        int col = nn * 16 + l15;
        rw[row * 64 + col] = acc[mm][nn][r];
      }
  __syncthreads();
  {
    int base = tid * 16;                     // 16 consecutive f32 of the 64x64 tile
    #pragma unroll
    for (int q = 0; q < 4; ++q) {
      f32x4 s = *(const f32x4*)(red + base + q * 4);
      #pragma unroll
      for (int wv = 1; wv < 4; ++wv)
        s += *(const f32x4*)(red + wv * 4096 + base + q * 4);
      int r  = (base + q * 4) >> 6;
      int cc = (base + q * 4) & 63;
      *(f32x4*)(out + (size_t)(row0 + r) * 4096 + f * 64 + cc) = s;
    }
  }
}

extern "C" void kernel_launch(void* const* d_in, const int* in_sizes, int n_in,
                              void* d_out, int out_size, void* d_ws, size_t ws_size,
                              hipStream_t stream) {
  const float* x = (const float*)d_in[0];    // (256, 4096) fp32
  const float* w = (const float*)d_in[1];    // (64, 64, 64) fp32
  float* out = (float*)d_out;                // (256, 4096) fp32

  u16* Xb = (u16*)d_ws;                      // 2 MB bf16 X

  xconv_kernel<<<256 * KDIM / 4 / 256, 256, 0, stream>>>(x, Xb);
  gemm_circ<<<dim3(64, 4), 256, 70144, stream>>>(Xb, w, out);
}

// Round 4
// 24.053 us; speedup vs baseline: 3.4923x; 1.1623x over previous
//
#include <hip/hip_runtime.h>

// out[b, f*64+n] = sum_c sum_j Xb[b, c*64+j] * w[f, c, (n-j)&63]
// One 512-thread block per (f, 64-row quarter) = 256 blocks = 1/CU, 8 waves
// = 2/SIMD (latency hiding). 8 waves split K 8-ways (wave wid owns c=8t+wid),
// NMACRO=8 macros x 512 K, A-tile 64x512 double-buffered (2x64KB) with G21
// XOR swizzle, per-wave circulant tables (stride-72 -> 16B-aligned b128),
// 8-way LDS reduce epilogue. One barrier per macro.

#define KDIM 4096
#define NMACRO 8

typedef __attribute__((ext_vector_type(8))) short s16x8;
typedef __attribute__((ext_vector_type(4))) float f32x4;
typedef unsigned short u16;

__device__ __forceinline__ u16 f2bf(float f) {
  unsigned int u = __float_as_uint(f);
  u += 0x7FFF + ((u >> 16) & 1);   // round-to-nearest-even
  return (u16)(u >> 16);
}

// ---- x (fp32, 256x4096) -> bf16 ----
__global__ __launch_bounds__(256) void xconv_kernel(const float* __restrict__ x,
                                                    u16* __restrict__ Xb) {
  int i = blockIdx.x * 256 + threadIdx.x;
  float4 v = ((const float4*)x)[i];
  union { u16 u[4]; uint2 v2; } o;
  o.u[0] = f2bf(v.x); o.u[1] = f2bf(v.y); o.u[2] = f2bf(v.z); o.u[3] = f2bf(v.w);
  *(uint2*)(Xb + (size_t)i * 4) = o.v2;
}

// ---- fused circulant GEMM ----
__global__ __launch_bounds__(512) void gemm_circ(const u16* __restrict__ Xb,
                                                 const float* __restrict__ w,
                                                 float* __restrict__ out) {
  extern __shared__ __align__(16) char pool[];   // 131072: 2 x 64KB A dbuf / epilogue
  __shared__ __align__(16) u16 Cs[8 * 576];      // 8 waves x (8 copies x 72) circulant

  const int tid  = threadIdx.x;
  const int lane = tid & 63;
  const int wid  = tid >> 6;                 // 0..7 = c-slot within macro
  const int l15  = lane & 15;
  const int lq   = lane >> 4;                // 0..3
  const int f    = blockIdx.x;               // 64; id%8=f%8 -> f-group per XCD
  const int row0 = blockIdx.y * 64;          // 4 row-quarters

  u16* CsW = Cs + wid * 576;

  // A staging addressing: 64 rows x 512 K bf16 = 64KB/macro = 8 chunks x 512thr x 16B.
  // Linear LDS dest d; source column pre-inverse-swizzled (G21).
  const u16* asrc[8];
  int adst[8];
  #pragma unroll
  for (int ch = 0; ch < 8; ++ch) {
    int d   = ch * 8192 + tid * 16;          // byte offset in one 64KB buffer
    int row = d >> 10;                       // 1024 B per row (512 x bf16)
    int sb  = (d & 1023) ^ ((row & 7) << 4);
    asrc[ch] = Xb + (size_t)(row0 + row) * KDIM + (sb >> 1);
    adst[ch] = d;
  }

  // w source: lane loads w[f][c][lane], c = 8t + wid -> advance 512 floats/macro
  const float* wsrc = w + (size_t)f * 4096 + wid * 64 + lane;

  // ---- prologue: macro 0 table + stage macro 0 into buffer 0
  {
    float vw0 = wsrc[0];
    #pragma unroll
    for (int ch = 0; ch < 8; ++ch)
      __builtin_amdgcn_global_load_lds(
          (const __attribute__((address_space(1))) void*)(asrc[ch]),
          (__attribute__((address_space(3))) void*)(pool + adst[ch]), 16, 0, 0);
    u16 bv = f2bf(vw0);
    #pragma unroll
    for (int m = 0; m < 8; ++m) {
      int i = (-(lane + m)) & 63;            // C_m[i] = w[(-i-m)&63]
      CsW[m * 72 + i] = bv;
      if (i < 8) CsW[m * 72 + i + 64] = bv;  // periodic duplicate
    }
  }
  __syncthreads();

  f32x4 acc[4][4] = {};

  for (int t = 0; t < NMACRO; ++t) {
    const int par = t & 1;
    float vw;
    if (t + 1 < NMACRO) {
      vw = wsrc[(t + 1) * 512];              // issue w prefetch FIRST (counted wait)
      #pragma unroll
      for (int ch = 0; ch < 8; ++ch)
        __builtin_amdgcn_global_load_lds(
            (const __attribute__((address_space(1))) void*)(asrc[ch] + (t + 1) * 512),
            (__attribute__((address_space(3))) void*)(pool + (par ^ 1) * 65536 + adst[ch]),
            16, 0, 0);
    }

    // ---- compute macro t: this wave's c-slice is k' in [wid*64, wid*64+64)
    const char* Abase = pool + par * 65536;
    #pragma unroll
    for (int kk = 0; kk < 2; ++kk) {
      s16x8 a[4], b[4];
      #pragma unroll
      for (int mm = 0; mm < 4; ++mm) {
        int row = mm * 16 + l15;
        int kb  = (wid * 64 + kk * 32 + lq * 8) * 2;
        a[mm] = *(const s16x8*)(Abase + row * 1024 + (kb ^ ((row & 7) << 4)));
      }
      #pragma unroll
      for (int nn = 0; nn < 4; ++nn) {
        int i0 = ((kk * 32 + lq * 8) - (nn * 16 + l15)) & 63;
        int ae = (i0 & 7) * 71 + i0;         // copy (i0&7), 16B-aligned
        b[nn] = *(const s16x8*)(CsW + ae);
      }
      #pragma unroll
      for (int mm = 0; mm < 4; ++mm)
        #pragma unroll
        for (int nn = 0; nn < 4; ++nn)
          acc[mm][nn] = __builtin_amdgcn_mfma_f32_16x16x32_bf16(a[mm], b[nn], acc[mm][nn], 0, 0, 0);
    }

    // ---- build next macro's table (wave-private; DS in-order per wave = safe)
    if (t + 1 < NMACRO) {
      u16 nb = f2bf(vw);
      #pragma unroll
      for (int m = 0; m < 8; ++m) {
        int i = (-(lane + m)) & 63;
        CsW[m * 72 + i] = nb;
        if (i < 8) CsW[m * 72 + i + 64] = nb;
      }
    }
    __syncthreads();                         // A dbuf handoff
  }

  // ---- epilogue: 8-way cross-wave K-reduce via LDS (reuse A region)
  float* red = (float*)pool;                 // 8 x 4096 f32 = 128 KB
  float* rw  = red + wid * 4096;
  #pragma unroll
  for (int mm = 0; mm < 4; ++mm)
    #pragma unroll
    for (int nn = 0; nn < 4; ++nn)
      #pragma unroll
      for (int r = 0; r < 4; ++r) {
        int row = mm * 16 + lq * 4 + r;      // m89-verified C/D layout
        int col = nn * 16 + l15;
        rw[row * 64 + col] = acc[mm][nn][r];
      }
  __syncthreads();
  #pragma unroll
  for (int p = 0; p < 2; ++p) {
    int e = p * 2048 + tid * 4;              // 4 consecutive f32 -> conflict-free
    f32x4 s = *(const f32x4*)(red + e);
    #pragma unroll
    for (int wv = 1; wv < 8; ++wv)
      s += *(const f32x4*)(red + wv * 4096 + e);
    int r  = e >> 6;
    int cc = e & 63;
    *(f32x4*)(out + (size_t)(row0 + r) * 4096 + f * 64 + cc) = s;
  }
}

extern "C" void kernel_launch(void* const* d_in, const int* in_sizes, int n_in,
                              void* d_out, int out_size, void* d_ws, size_t ws_size,
                              hipStream_t stream) {
  const float* x = (const float*)d_in[0];    // (256, 4096) fp32
  const float* w = (const float*)d_in[1];    // (64, 64, 64) fp32
  float* out = (float*)d_out;                // (256, 4096) fp32

  u16* Xb = (u16*)d_ws;                      // 2 MB bf16 X

  xconv_kernel<<<256 * KDIM / 4 / 256, 256, 0, stream>>>(x, Xb);
  gemm_circ<<<dim3(64, 4), 512, 131072, stream>>>(Xb, w, out);
}

// Round 5
// 21.245 us; speedup vs baseline: 3.9538x; 1.1321x over previous
//
#include <hip/hip_runtime.h>

// out[b, f*64+n] = sum_c sum_j x[b, c*64+j] * w[f, c, (n-j)&63]
// R5: A (X) is pre-packed in MFMA-fragment order -> gemm reads A straight
// from L2 via coalesced global b128 loads (VMEM pipe). LDS holds only the
// tiny circulant tables (dbuf, shared per c-slot) + epilogue reduce.
// 256 blocks x 1024 thr (16 waves = 4/SIMD). mfma_f32_32x32x16_bf16.
// Wave (cslot, half): rows half*32+[0,32), cols f*64+[0,64), K split 8-way.

#define KDIM 4096

typedef __attribute__((ext_vector_type(8)))  short s16x8;
typedef __attribute__((ext_vector_type(4)))  float f32x4;
typedef __attribute__((ext_vector_type(16))) float f32x16;
typedef unsigned short u16;

__device__ __forceinline__ u16 f2bf(float f) {
  unsigned int u = __float_as_uint(f);
  u += 0x7FFF + ((u >> 16) & 1);   // round-to-nearest-even
  return (u16)(u >> 16);
}

// ---- pack x (fp32 256x4096) -> Xp bf16 in 32x32x16-A-fragment order ----
// frag id (c, rg, kk); 16B unit u = ((c*8+rg)*4+kk)*64 + lane;
// content(lane, j) = x[rg*32 + (lane&31)][c*64 + kk*16 + (lane>>5)*8 + j]
__global__ __launch_bounds__(256) void pack_kernel(const float* __restrict__ x,
                                                   u16* __restrict__ Xp) {
  int g   = blockIdx.x * 256 + threadIdx.x;   // 131072 chunks of 8 elems
  int row = g >> 9;
  int k8  = g & 511;
  const float4* src = (const float4*)(x + ((size_t)row << 12) + (k8 << 3));
  float4 v0 = src[0], v1 = src[1];
  union { u16 u[8]; uint4 v; } o;
  o.u[0] = f2bf(v0.x); o.u[1] = f2bf(v0.y); o.u[2] = f2bf(v0.z); o.u[3] = f2bf(v0.w);
  o.u[4] = f2bf(v1.x); o.u[5] = f2bf(v1.y); o.u[6] = f2bf(v1.z); o.u[7] = f2bf(v1.w);
  int c  = k8 >> 3;
  int r3 = k8 & 7;
  int kk = r3 >> 1;
  int lh = r3 & 1;
  int lane = (lh << 5) | (row & 31);
  int rg = row >> 5;
  size_t u = ((size_t)((c * 8 + rg) * 4 + kk) << 6) + lane;   // 16B units
  *(uint4*)(Xp + (u << 3)) = o.v;
}

// ---- GEMM: A-frags from L2, circulant tables in LDS ----
__global__ __launch_bounds__(1024) void gemm_direct(const u16* __restrict__ Xp,
                                                    const float* __restrict__ w,
                                                    float* __restrict__ out) {
  extern __shared__ __align__(16) char pool[];     // 131072 B epilogue red
  __shared__ __align__(16) u16 Cs[2][8][576];      // dbuf x cslot x (8 copies x 72)

  const int tid   = threadIdx.x;
  const int lane  = tid & 63;
  const int wid   = tid >> 6;        // 0..15
  const int cslot = wid & 7;         // c = 8t + cslot
  const int half  = wid >> 3;        // row half (0: rows 0-31, 1: 32-63)
  const int l31   = lane & 31;
  const int lh    = lane >> 5;
  const int f     = blockIdx.x >> 2; // XCD = bid%8 -> fixed batch-quarter per XCD
  const int q     = blockIdx.x & 3;
  const int rg    = q * 2 + half;    // 32-row group in batch

  // b-frag LDS offsets (u16 units within a table), hoisted: s = 0..3
  int bofs[4];
  #pragma unroll
  for (int s = 0; s < 4; ++s) {
    int i0 = (lh * 8 - l31 - 16 * s) & 63;
    bofs[s] = (i0 & 7) * 72 + (i0 & ~7);           // copy i0&7, 16B-aligned
  }

  // A-frag base: u16 idx = ((c*8+rg)*4+kk)*512 + lane*8 ; c step 8 -> +131072
  const u16* abase = Xp + ((size_t)(cslot * 8 + rg) * 4 * 512 + lane * 8);

  const float* wrow = w + ((size_t)f << 12) + (cslot << 6) + lane;

  // prologue: table for t=0 into set 0 (builders = half 0)
  if (half == 0) {
    u16 bv = f2bf(wrow[0]);
    #pragma unroll
    for (int m = 0; m < 8; ++m) {
      int i = (-(lane + m)) & 63;                  // C_m[i] = w[(-i-m)&63]
      Cs[0][cslot][m * 72 + i] = bv;
    }
  }

  f32x16 acc0 = {}, acc1 = {};
  s16x8 a[4], an[4];
  #pragma unroll
  for (int kk = 0; kk < 4; ++kk)
    a[kk] = *(const s16x8*)(abase + kk * 512);

  __syncthreads();                                 // table(0) visible

  for (int t = 0; t < 8; ++t) {
    const u16* T = &Cs[t & 1][cslot][0];
    float vw;
    if (t < 7) {                                   // prefetch next c
      if (half == 0) vw = wrow[(t + 1) * 512];
      #pragma unroll
      for (int kk = 0; kk < 4; ++kk)
        an[kk] = *(const s16x8*)(abase + (size_t)(t + 1) * 131072 + kk * 512);
    }
    s16x8 b[4];
    #pragma unroll
    for (int s = 0; s < 4; ++s)
      b[s] = *(const s16x8*)(T + bofs[s]);
    #pragma unroll
    for (int kk = 0; kk < 4; ++kk) {
      acc0 = __builtin_amdgcn_mfma_f32_32x32x16_bf16(a[kk], b[(0 - kk) & 3], acc0, 0, 0, 0);
      acc1 = __builtin_amdgcn_mfma_f32_32x32x16_bf16(a[kk], b[(2 - kk) & 3], acc1, 0, 0, 0);
    }
    if (t < 7) {
      if (half == 0) {                             // build t+1 into other set
        u16 nb = f2bf(vw);
        #pragma unroll
        for (int m = 0; m < 8; ++m) {
          int i = (-(lane + m)) & 63;
          Cs[(t + 1) & 1][cslot][m * 72 + i] = nb;
        }
      }
      #pragma unroll
      for (int kk = 0; kk < 4; ++kk) a[kk] = an[kk];
    }
    __syncthreads();   // build(t+1) visible; readers done with set t
  }

  // ---- epilogue: 8-way c-slot reduce via LDS in frag layout ----
  float* red = (float*)pool;   // [wid][nn][lane][16 f32] = 128 KB
  {
    float* r0 = red + ((size_t)(wid * 2 + 0) * 64 + lane) * 16;
    float* r1 = red + ((size_t)(wid * 2 + 1) * 64 + lane) * 16;
    #pragma unroll
    for (int i = 0; i < 4; ++i) {
      f32x4 v0 = {acc0[4 * i], acc0[4 * i + 1], acc0[4 * i + 2], acc0[4 * i + 3]};
      f32x4 v1 = {acc1[4 * i], acc1[4 * i + 1], acc1[4 * i + 2], acc1[4 * i + 3]};
      *(f32x4*)(r0 + 4 * i) = v0;
      *(f32x4*)(r1 + 4 * i) = v1;
    }
  }
  __syncthreads();
  {
    int rq  = tid & 3;              // reg quad (regs rq*4 .. rq*4+3)
    int ln  = (tid >> 2) & 63;      // source lane
    int nn2 = (tid >> 8) & 1;
    int hf  = tid >> 9;             // source half
    f32x4 s = {};
    #pragma unroll
    for (int cs = 0; cs < 8; ++cs)
      s += *(const f32x4*)(red + ((size_t)(((hf * 8 + cs) * 2) + nn2) * 64 + ln) * 16 + rq * 4);
    // C/D layout (m74/m101): col = lane&31, row = (reg&3) + 8*(reg>>2) + 4*(lane>>5)
    int colg = f * 64 + nn2 * 32 + (ln & 31);
    int rowb = q * 64 + hf * 32 + 8 * rq + 4 * (ln >> 5);
    #pragma unroll
    for (int e = 0; e < 4; ++e)
      out[(size_t)(rowb + e) * 4096 + colg] = s[e];
  }
}

extern "C" void kernel_launch(void* const* d_in, const int* in_sizes, int n_in,
                              void* d_out, int out_size, void* d_ws, size_t ws_size,
                              hipStream_t stream) {
  const float* x = (const float*)d_in[0];    // (256, 4096) fp32
  const float* w = (const float*)d_in[1];    // (64, 64, 64) fp32
  float* out = (float*)d_out;                // (256, 4096) fp32

  u16* Xp = (u16*)d_ws;                      // 2 MB packed bf16 X

  pack_kernel<<<512, 256, 0, stream>>>(x, Xp);
  gemm_direct<<<256, 1024, 131072, stream>>>(Xp, w, out);
}

// Round 6
// 21.222 us; speedup vs baseline: 3.9582x; 1.0011x over previous
//
#include <hip/hip_runtime.h>

// out[b, f*64+n] = sum_c sum_j x[b, c*64+j] * w[f, c, (n-j)&63]
// R6: barrier-free main loop. All 64 circulant tables built in LDS up front
// (one barrier); K-loop reads A-frags from L2 (pre-packed, prefetch-1 in regs)
// and B-frags from read-only LDS -- no syncs, waves free-run (4/SIMD).
// 256 blocks x 1024 thr, mfma_f32_32x32x16_bf16, log2 LDS reduce epilogue.

#define KDIM 4096

typedef __attribute__((ext_vector_type(8)))  short s16x8;
typedef __attribute__((ext_vector_type(4)))  float f32x4;
typedef __attribute__((ext_vector_type(16))) float f32x16;
typedef unsigned short u16;

__device__ __forceinline__ u16 f2bf(float f) {
  unsigned int u = __float_as_uint(f);
  u += 0x7FFF + ((u >> 16) & 1);   // round-to-nearest-even
  return (u16)(u >> 16);
}

// ---- pack x (fp32 256x4096) -> Xp bf16 in 32x32x16-A-fragment order ----
// frag id (c, rg, kk); 16B unit u = ((c*8+rg)*4+kk)*64 + lane;
// content(lane, j) = x[rg*32 + (lane&31)][c*64 + kk*16 + (lane>>5)*8 + j]
__global__ __launch_bounds__(256) void pack_kernel(const float* __restrict__ x,
                                                   u16* __restrict__ Xp) {
  int g   = blockIdx.x * 256 + threadIdx.x;   // 131072 chunks of 8 elems
  int row = g >> 9;
  int k8  = g & 511;
  const float4* src = (const float4*)(x + ((size_t)row << 12) + (k8 << 3));
  float4 v0 = src[0], v1 = src[1];
  union { u16 u[8]; uint4 v; } o;
  o.u[0] = f2bf(v0.x); o.u[1] = f2bf(v0.y); o.u[2] = f2bf(v0.z); o.u[3] = f2bf(v0.w);
  o.u[4] = f2bf(v1.x); o.u[5] = f2bf(v1.y); o.u[6] = f2bf(v1.z); o.u[7] = f2bf(v1.w);
  int c  = k8 >> 3;
  int r3 = k8 & 7;
  int kk = r3 >> 1;
  int lh = r3 & 1;
  int lane = (lh << 5) | (row & 31);
  int rg = row >> 5;
  size_t u = ((size_t)((c * 8 + rg) * 4 + kk) << 6) + lane;   // 16B units
  *(uint4*)(Xp + (u << 3)) = o.v;
}

// ---- barrier-free fused GEMM ----
__global__ __launch_bounds__(1024, 4) void gemm_free(const u16* __restrict__ Xp,
                                                     const float* __restrict__ w,
                                                     float* __restrict__ out) {
  extern __shared__ __align__(16) char pool[];   // 73728 B: tables, then reduce
  u16* tab = (u16*)pool;                         // [c][576] u16, c = 0..63

  const int tid   = threadIdx.x;
  const int lane  = tid & 63;
  const int wid   = tid >> 6;        // 0..15
  const int cslot = wid & 7;         // c = 8t + cslot
  const int half  = wid >> 3;        // 32-row half of the 64-row quarter
  const int l31   = lane & 31;
  const int lh    = lane >> 5;
  const int f     = blockIdx.x >> 2;
  const int q     = blockIdx.x & 3;
  const int rg    = q * 2 + half;    // 32-row group in batch

  // ---- build all 64 tables: wave wid builds c = wid*4 .. wid*4+3
  // table c: C_m[i] = bf16(w[f][c][(-i-m)&63]), copies at stride 72 u16
  const float* wf = w + ((size_t)f << 12);
  #pragma unroll
  for (int j = 0; j < 4; ++j) {
    int c = wid * 4 + j;
    u16 bv = f2bf(wf[(c << 6) + lane]);
    u16* T = tab + c * 576;
    #pragma unroll
    for (int m = 0; m < 8; ++m) {
      int i = (-(lane + m)) & 63;
      T[m * 72 + i] = bv;
    }
  }

  // b-frag offsets within a table (verified in R5): copy i0&7, 16B-aligned
  int bofs[4];
  #pragma unroll
  for (int s = 0; s < 4; ++s) {
    int i0 = (lh * 8 - l31 - 16 * s) & 63;
    bofs[s] = (i0 & 7) * 71 + i0;
  }

  // A-frag base (u16): ((c*8+rg)*4+kk)*512 + lane*8; c step 8 -> +131072
  const u16* abase = Xp + ((size_t)(cslot * 8 + rg) * 2048 + lane * 8);

  f32x16 acc0 = {}, acc1 = {};
  s16x8 a0, a1, a2, a3, n0, n1, n2, n3;
  a0 = *(const s16x8*)(abase);
  a1 = *(const s16x8*)(abase + 512);
  a2 = *(const s16x8*)(abase + 1024);
  a3 = *(const s16x8*)(abase + 1536);

  __syncthreads();                   // tables visible; ONLY barrier before epilogue

  #pragma unroll
  for (int t = 0; t < 8; ++t) {
    if (t < 7) {                     // prefetch next c's A-frags (L2)
      const u16* nb = abase + (size_t)(t + 1) * 131072;
      n0 = *(const s16x8*)(nb);
      n1 = *(const s16x8*)(nb + 512);
      n2 = *(const s16x8*)(nb + 1024);
      n3 = *(const s16x8*)(nb + 1536);
    }
    const u16* T = tab + (8 * t + cslot) * 576;
    s16x8 b0 = *(const s16x8*)(T + bofs[0]);
    s16x8 b1 = *(const s16x8*)(T + bofs[1]);
    s16x8 b2 = *(const s16x8*)(T + bofs[2]);
    s16x8 b3 = *(const s16x8*)(T + bofs[3]);
    // kk = 0..3: acc0 uses b[(0-kk)&3], acc1 uses b[(2-kk)&3]  (R5-verified)
    acc0 = __builtin_amdgcn_mfma_f32_32x32x16_bf16(a0, b0, acc0, 0, 0, 0);
    acc1 = __builtin_amdgcn_mfma_f32_32x32x16_bf16(a0, b2, acc1, 0, 0, 0);
    acc0 = __builtin_amdgcn_mfma_f32_32x32x16_bf16(a1, b3, acc0, 0, 0, 0);
    acc1 = __builtin_amdgcn_mfma_f32_32x32x16_bf16(a1, b1, acc1, 0, 0, 0);
    acc0 = __builtin_amdgcn_mfma_f32_32x32x16_bf16(a2, b2, acc0, 0, 0, 0);
    acc1 = __builtin_amdgcn_mfma_f32_32x32x16_bf16(a2, b0, acc1, 0, 0, 0);
    acc0 = __builtin_amdgcn_mfma_f32_32x32x16_bf16(a3, b1, acc0, 0, 0, 0);
    acc1 = __builtin_amdgcn_mfma_f32_32x32x16_bf16(a3, b3, acc1, 0, 0, 0);
    if (t < 7) { a0 = n0; a1 = n1; a2 = n2; a3 = n3; }
  }

  // ---- epilogue: 8-way cslot log2 reduce in LDS (reuse table region) ----
  __syncthreads();                   // everyone done reading tables
  float* red = (float*)pool;         // 8 slots x 8 KB = 64 KB
  // slot layout: [x(0..7)][lane] of f32x4 -> lanes contiguous 16B, conflict-free

  #define WRITE_ACC(k)                                                        \
    { float* Bf = red + (size_t)(half * 4 + (k)) * 2048;                      \
      _Pragma("unroll")                                                       \
      for (int i = 0; i < 4; ++i) {                                           \
        f32x4 v0 = {acc0[4*i], acc0[4*i+1], acc0[4*i+2], acc0[4*i+3]};        \
        f32x4 v1 = {acc1[4*i], acc1[4*i+1], acc1[4*i+2], acc1[4*i+3]};        \
        *(f32x4*)(Bf + (size_t)i * 256 + lane * 4) = v0;                      \
        *(f32x4*)(Bf + (size_t)(i + 4) * 256 + lane * 4) = v1;                \
      } }
  #define ADD_ACC(k)                                                          \
    { const float* Bf = red + (size_t)(half * 4 + (k)) * 2048;                \
      _Pragma("unroll")                                                       \
      for (int i = 0; i < 4; ++i) {                                           \
        f32x4 v0 = *(const f32x4*)(Bf + (size_t)i * 256 + lane * 4);          \
        f32x4 v1 = *(const f32x4*)(Bf + (size_t)(i + 4) * 256 + lane * 4);    \
        _Pragma("unroll")                                                     \
        for (int e = 0; e < 4; ++e) {                                         \
          acc0[4*i+e] += v0[e];                                               \
          acc1[4*i+e] += v1[e];                                               \
        }                                                                     \
      } }

  if (cslot >= 4) WRITE_ACC(cslot - 4);
  __syncthreads();
  if (cslot < 4) ADD_ACC(cslot);
  __syncthreads();
  if (cslot == 2 || cslot == 3) WRITE_ACC(cslot - 2);
  __syncthreads();
  if (cslot < 2) ADD_ACC(cslot);
  __syncthreads();
  if (cslot == 1) WRITE_ACC(0);
  __syncthreads();
  if (cslot == 0) {
    ADD_ACC(0);
    // C/D layout (m74/m101): col = lane&31, row = (reg&3)+8*(reg>>2)+4*(lane>>5)
    const int colg = (f << 6) + l31;
    const int rowb = q * 64 + half * 32 + 4 * lh;
    #pragma unroll
    for (int r = 0; r < 16; ++r) {
      int row = rowb + (r & 3) + 8 * (r >> 2);
      out[(size_t)row * 4096 + colg]      = acc0[r];
      out[(size_t)row * 4096 + colg + 32] = acc1[r];
    }
  }
}

extern "C" void kernel_launch(void* const* d_in, const int* in_sizes, int n_in,
                              void* d_out, int out_size, void* d_ws, size_t ws_size,
                              hipStream_t stream) {
  const float* x = (const float*)d_in[0];    // (256, 4096) fp32
  const float* w = (const float*)d_in[1];    // (64, 64, 64) fp32
  float* out = (float*)d_out;                // (256, 4096) fp32

  u16* Xp = (u16*)d_ws;                      // 2 MB packed bf16 X

  pack_kernel<<<512, 256, 0, stream>>>(x, Xp);
  gemm_free<<<256, 1024, 73728, stream>>>(Xp, w, out);
}

// Round 7
// 20.804 us; speedup vs baseline: 4.0376x; 1.0201x over previous
//
#include <hip/hip_runtime.h>

// out[b, f*64+n] = sum_c sum_j x[b, c*64+j] * w[f, c, (n-j)&63]
// R7: pack rewritten as LDS-transpose -> coalesced reads AND coalesced
// fragment writes (R6 pack wrote 131072 scattered 16B lines). GEMM unchanged:
// barrier-free K-loop, A-frags streamed from L2 (pre-packed), circulant
// tables in LDS, 256 blocks x 1024 thr, mfma_f32_32x32x16_bf16.

#define KDIM 4096

typedef __attribute__((ext_vector_type(8)))  short s16x8;
typedef __attribute__((ext_vector_type(4)))  float f32x4;
typedef __attribute__((ext_vector_type(16))) float f32x16;
typedef unsigned short u16;

__device__ __forceinline__ u16 f2bf(float f) {
  unsigned int u = __float_as_uint(f);
  u += 0x7FFF + ((u >> 16) & 1);   // round-to-nearest-even
  return (u16)(u >> 16);
}

// ---- pack x (fp32 256x4096) -> Xp bf16 in 32x32x16-A-fragment order ----
// Xp 16B-unit u = ((c*8+rg)*4+kk)*64 + lane;
// content(lane, j) = x[rg*32 + (lane&31)][c*64 + kk*16 + (lane>>5)*8 + j]
// Block (rg, cg): rows rg*32..+31, c = cg*4..+3 (k = cg*256..+255).
// LDS tile [32][264] u16: row stride 33 16B-units (odd) -> residues spread.
__global__ __launch_bounds__(256) void pack_kernel(const float* __restrict__ x,
                                                   u16* __restrict__ Xp) {
  __shared__ __align__(16) u16 tile[32 * 264];
  const int tid = threadIdx.x;
  const int rg  = blockIdx.x >> 4;
  const int cg  = blockIdx.x & 15;

  // phase 1: coalesced read 32 rows x 256 f32, convert, LDS write
  #pragma unroll
  for (int i = 0; i < 4; ++i) {
    int g    = i * 2048 + tid * 8;        // 8 consecutive floats
    int row  = g >> 8;
    int kloc = g & 255;
    const float4* src = (const float4*)(x + (size_t)(rg * 32 + row) * 4096 + cg * 256 + kloc);
    float4 v0 = src[0], v1 = src[1];
    union { u16 u[8]; uint4 v; } o;
    o.u[0] = f2bf(v0.x); o.u[1] = f2bf(v0.y); o.u[2] = f2bf(v0.z); o.u[3] = f2bf(v0.w);
    o.u[4] = f2bf(v1.x); o.u[5] = f2bf(v1.y); o.u[6] = f2bf(v1.z); o.u[7] = f2bf(v1.w);
    *(uint4*)(tile + row * 264 + kloc) = o.v;
  }
  __syncthreads();

  // phase 2: write 16 frags (4 c' x 4 kk), each 64 lanes x 16B coalesced
  const int lane = tid & 63;
  const int fw   = tid >> 6;              // 0..3
  #pragma unroll
  for (int i = 0; i < 4; ++i) {
    int fidx = i * 4 + fw;                // 0..15
    int cl   = fidx >> 2;                 // c' 0..3
    int kk   = fidx & 3;
    int c    = cg * 4 + cl;
    uint4 v = *(const uint4*)(tile + (lane & 31) * 264 + cl * 64 + kk * 16 + (lane >> 5) * 8);
    size_t u = ((size_t)((c * 8 + rg) * 4 + kk) << 6) + lane;
    *(uint4*)(Xp + (u << 3)) = v;
  }
}

// ---- barrier-free fused GEMM (unchanged from R6) ----
__global__ __launch_bounds__(1024, 4) void gemm_free(const u16* __restrict__ Xp,
                                                     const float* __restrict__ w,
                                                     float* __restrict__ out) {
  extern __shared__ __align__(16) char pool[];   // 73728 B: tables, then reduce
  u16* tab = (u16*)pool;                         // [c][576] u16, c = 0..63

  const int tid   = threadIdx.x;
  const int lane  = tid & 63;
  const int wid   = tid >> 6;        // 0..15
  const int cslot = wid & 7;         // c = 8t + cslot
  const int half  = wid >> 3;        // 32-row half of the 64-row quarter
  const int l31   = lane & 31;
  const int lh    = lane >> 5;
  const int f     = blockIdx.x >> 2;
  const int q     = blockIdx.x & 3;
  const int rg    = q * 2 + half;    // 32-row group in batch

  // build all 64 tables: wave wid builds c = wid*4 .. wid*4+3
  const float* wf = w + ((size_t)f << 12);
  #pragma unroll
  for (int j = 0; j < 4; ++j) {
    int c = wid * 4 + j;
    u16 bv = f2bf(wf[(c << 6) + lane]);
    u16* T = tab + c * 576;
    #pragma unroll
    for (int m = 0; m < 8; ++m) {
      int i = (-(lane + m)) & 63;
      T[m * 72 + i] = bv;
    }
  }

  int bofs[4];
  #pragma unroll
  for (int s = 0; s < 4; ++s) {
    int i0 = (lh * 8 - l31 - 16 * s) & 63;
    bofs[s] = (i0 & 7) * 71 + i0;    // copy i0&7, 16B-aligned window
  }

  const u16* abase = Xp + ((size_t)(cslot * 8 + rg) * 2048 + lane * 8);

  f32x16 acc0 = {}, acc1 = {};
  s16x8 a0, a1, a2, a3, n0, n1, n2, n3;
  a0 = *(const s16x8*)(abase);
  a1 = *(const s16x8*)(abase + 512);
  a2 = *(const s16x8*)(abase + 1024);
  a3 = *(const s16x8*)(abase + 1536);

  __syncthreads();                   // tables visible; only barrier before epilogue

  #pragma unroll
  for (int t = 0; t < 8; ++t) {
    if (t < 7) {
      const u16* nb = abase + (size_t)(t + 1) * 131072;
      n0 = *(const s16x8*)(nb);
      n1 = *(const s16x8*)(nb + 512);
      n2 = *(const s16x8*)(nb + 1024);
      n3 = *(const s16x8*)(nb + 1536);
    }
    const u16* T = tab + (8 * t + cslot) * 576;
    s16x8 b0 = *(const s16x8*)(T + bofs[0]);
    s16x8 b1 = *(const s16x8*)(T + bofs[1]);
    s16x8 b2 = *(const s16x8*)(T + bofs[2]);
    s16x8 b3 = *(const s16x8*)(T + bofs[3]);
    acc0 = __builtin_amdgcn_mfma_f32_32x32x16_bf16(a0, b0, acc0, 0, 0, 0);
    acc1 = __builtin_amdgcn_mfma_f32_32x32x16_bf16(a0, b2, acc1, 0, 0, 0);
    acc0 = __builtin_amdgcn_mfma_f32_32x32x16_bf16(a1, b3, acc0, 0, 0, 0);
    acc1 = __builtin_amdgcn_mfma_f32_32x32x16_bf16(a1, b1, acc1, 0, 0, 0);
    acc0 = __builtin_amdgcn_mfma_f32_32x32x16_bf16(a2, b2, acc0, 0, 0, 0);
    acc1 = __builtin_amdgcn_mfma_f32_32x32x16_bf16(a2, b0, acc1, 0, 0, 0);
    acc0 = __builtin_amdgcn_mfma_f32_32x32x16_bf16(a3, b1, acc0, 0, 0, 0);
    acc1 = __builtin_amdgcn_mfma_f32_32x32x16_bf16(a3, b3, acc1, 0, 0, 0);
    if (t < 7) { a0 = n0; a1 = n1; a2 = n2; a3 = n3; }
  }

  // epilogue: 8-way cslot log2 reduce in LDS (reuse table region)
  __syncthreads();
  float* red = (float*)pool;

  #define WRITE_ACC(k)                                                        \
    { float* Bf = red + (size_t)(half * 4 + (k)) * 2048;                      \
      _Pragma("unroll")                                                       \
      for (int i = 0; i < 4; ++i) {                                           \
        f32x4 v0 = {acc0[4*i], acc0[4*i+1], acc0[4*i+2], acc0[4*i+3]};        \
        f32x4 v1 = {acc1[4*i], acc1[4*i+1], acc1[4*i+2], acc1[4*i+3]};        \
        *(f32x4*)(Bf + (size_t)i * 256 + lane * 4) = v0;                      \
        *(f32x4*)(Bf + (size_t)(i + 4) * 256 + lane * 4) = v1;                \
      } }
  #define ADD_ACC(k)                                                          \
    { const float* Bf = red + (size_t)(half * 4 + (k)) * 2048;                \
      _Pragma("unroll")                                                       \
      for (int i = 0; i < 4; ++i) {                                           \
        f32x4 v0 = *(const f32x4*)(Bf + (size_t)i * 256 + lane * 4);          \
        f32x4 v1 = *(const f32x4*)(Bf + (size_t)(i + 4) * 256 + lane * 4);    \
        _Pragma("unroll")                                                     \
        for (int e = 0; e < 4; ++e) {                                         \
          acc0[4*i+e] += v0[e];                                               \
          acc1[4*i+e] += v1[e];                                               \
        }                                                                     \
      } }

  if (cslot >= 4) WRITE_ACC(cslot - 4);
  __syncthreads();
  if (cslot < 4) ADD_ACC(cslot);
  __syncthreads();
  if (cslot == 2 || cslot == 3) WRITE_ACC(cslot - 2);
  __syncthreads();
  if (cslot < 2) ADD_ACC(cslot);
  __syncthreads();
  if (cslot == 1) WRITE_ACC(0);
  __syncthreads();
  if (cslot == 0) {
    ADD_ACC(0);
    const int colg = (f << 6) + l31;
    const int rowb = q * 64 + half * 32 + 4 * lh;
    #pragma unroll
    for (int r = 0; r < 16; ++r) {
      int row = rowb + (r & 3) + 8 * (r >> 2);
      out[(size_t)row * 4096 + colg]      = acc0[r];
      out[(size_t)row * 4096 + colg + 32] = acc1[r];
    }
  }
}

extern "C" void kernel_launch(void* const* d_in, const int* in_sizes, int n_in,
                              void* d_out, int out_size, void* d_ws, size_t ws_size,
                              hipStream_t stream) {
  const float* x = (const float*)d_in[0];    // (256, 4096) fp32
  const float* w = (const float*)d_in[1];    // (64, 64, 64) fp32
  float* out = (float*)d_out;                // (256, 4096) fp32

  u16* Xp = (u16*)d_ws;                      // 2 MB packed bf16 X

  pack_kernel<<<128, 256, 0, stream>>>(x, Xp);
  gemm_free<<<256, 1024, 73728, stream>>>(Xp, w, out);
}